// Round 8
// baseline (84.665 us; speedup 1.0000x reference)
//
#include <hip/hip_runtime.h>

// Comb filter: y[n] = x[n-D] + f*y[n-D], y[n]=0 for n<D.
// N = 16777216, D = 4096 -> 4096 independent chains of K = 4096 steps each.
//
// SINGLE-PASS decoupled-lookback scan, v3.
// R6 lesson: acquire in the poll loop -> invalidate storm (2.3 ms).
// R7 lesson: bypass (sc0sc1) loads for ALL lookback data -> latency-bound
//            drip, ~85 us.
// v3 idiom (the rocPRIM/MI300 pattern):
//   - carry stores: relaxed agent-scope bypass (land at L3; drained by the
//     vmcnt(0) in __syncthreads before the flag store).
//   - flag poll: wave 0 only, RELAXED bypass loads + s_sleep.
//   - after poll success: ONE acquire load per block -> single buffer_inv
//     (invalidates stale L1/L2 lines, incl. lines cached from the previous
//     graph replay).
//   - lookback data: NORMAL cached float2 loads (L2/L3-allocating, full MLP).
//   - lookback math: order-free weighted sum, descending t, windows of 4,
//     fixed association -> bit-deterministic (absmax 0 in R4-R7).
// x is read from HBM exactly once and stays in registers for the emit.
// ws layout: [0] ticket | [64B..] 1024 flags | [8KB..] carries (2 MiB).

#define N_TOTAL 16777216
#define D       4096
#define K_STEPS (N_TOTAL / D)    // 4096
#define SEGS    128              // segments per chain
#define SEGLEN  (K_STEPS / SEGS) // 32 steps per segment
#define D2      (D / 2)          // 2048 float2 per k-row
#define D4      (D / 4)          // 1024 float4 per k-row
#define GROUPS  8                // chain-groups per segment row (float2 path)
#define WS_FLAGS_OFF   16        // in u32s (64 B)
#define WS_CARRY_OFF   8192      // bytes
#define WS_NEEDED      (WS_CARRY_OFF + SEGS * D * 4)

__global__ __launch_bounds__(256, 4)
void comb_fused(const float* __restrict__ x, const float* __restrict__ fptr,
                float* __restrict__ out, unsigned int* __restrict__ ws_u32,
                float2* __restrict__ carries) {
    unsigned int* ticket = ws_u32;
    unsigned int* flags  = ws_u32 + WS_FLAGS_OFF;

    __shared__ unsigned int s_rank;
    if (threadIdx.x == 0)
        s_rank = __hip_atomic_fetch_add(ticket, 1u, __ATOMIC_RELAXED,
                                        __HIP_MEMORY_SCOPE_AGENT);
    __syncthreads();
    const unsigned int rank = s_rank;
    const int s  = rank >> 3;                   // 0..127
    const int g  = rank & 7;                    // 0..7
    const int c2 = g * 256 + threadIdx.x;       // float2 chain index 0..2047

    const float f = fptr[0];
    const float2* __restrict__ xp = (const float2*)x;
    float2* __restrict__ op = (float2*)out;
    const int base = s * SEGLEN * D2 + c2;

    // ---- Phase 1: preload x into regs, local carry, publish (bypass) ----
    float2 xa[SEGLEN];
    #pragma unroll
    for (int k = 0; k < SEGLEN; ++k) xa[k] = xp[base + k * D2];

    float2 C = make_float2(0.f, 0.f);
    #pragma unroll
    for (int k = 0; k < SEGLEN; ++k) {
        C.x = f * C.x + xa[k].x;
        C.y = f * C.y + xa[k].y;
    }
    unsigned long long craw;
    __builtin_memcpy(&craw, &C, 8);
    __hip_atomic_store((unsigned long long*)&carries[s * D2 + c2], craw,
                       __ATOMIC_RELAXED, __HIP_MEMORY_SCOPE_AGENT);
    __syncthreads();   // vmcnt(0) drain -> all carry stores at L3
    if (threadIdx.x == 0)
        __hip_atomic_store(&flags[s * GROUPS + g], 1u, __ATOMIC_RELEASE,
                           __HIP_MEMORY_SCOPE_AGENT);

    // fL = f^SEGLEN via 5 squarings (SEGLEN = 32)
    float fL = f * f;
    fL = fL * fL; fL = fL * fL; fL = fL * fL; fL = fL * fL;
    const float fL2 = fL * fL;
    const float fL4 = fL2 * fL2;

    // ---- Wave-0 relaxed poll, then ONE acquire (single buffer_inv) ----
    if (threadIdx.x < 64 && s > 0) {
        const int l = threadIdx.x;
        for (;;) {
            bool ok0 = (l >= s) ||
                (__hip_atomic_load(&flags[l * GROUPS + g], __ATOMIC_RELAXED,
                                   __HIP_MEMORY_SCOPE_AGENT) != 0u);
            bool ok1 = (l + 64 >= s) ||
                (__hip_atomic_load(&flags[(l + 64) * GROUPS + g], __ATOMIC_RELAXED,
                                   __HIP_MEMORY_SCOPE_AGENT) != 0u);
            if (__all(ok0 && ok1)) break;
            __builtin_amdgcn_s_sleep(1);
        }
        if (threadIdx.x == 0)  // acquire fence: invalidate stale L1/L2 once
            (void)__hip_atomic_load(&flags[(s - 1) * GROUPS + g],
                                    __ATOMIC_ACQUIRE, __HIP_MEMORY_SCOPE_AGENT);
    }
    __syncthreads();   // phase-2 loads ordered after the poll + invalidate

    // ---- Phase 2: order-free weighted lookback, NORMAL cached loads ----
    const float2* __restrict__ cp = carries;
    float2 Y0 = make_float2(0.f, 0.f), Y1 = Y0, Y2 = Y0, Y3 = Y0;
    float w = 1.f;
    int t = s - 1;
    for (; t >= 3; t -= 4) {
        float2 C0 = cp[(t    ) * D2 + c2];
        float2 C1 = cp[(t - 1) * D2 + c2];
        float2 C2 = cp[(t - 2) * D2 + c2];
        float2 C3 = cp[(t - 3) * D2 + c2];
        const float w0 = w, w1 = w * fL, w2 = w * fL2, w3 = w1 * fL2;
        Y0.x += w0 * C0.x; Y0.y += w0 * C0.y;
        Y1.x += w1 * C1.x; Y1.y += w1 * C1.y;
        Y2.x += w2 * C2.x; Y2.y += w2 * C2.y;
        Y3.x += w3 * C3.x; Y3.y += w3 * C3.y;
        w = w * fL4;
    }
    for (; t >= 0; --t) {
        float2 Ct = cp[t * D2 + c2];
        Y0.x += w * Ct.x; Y0.y += w * Ct.y;
        w *= fL;
    }
    float2 y;
    y.x = (Y0.x + Y1.x) + (Y2.x + Y3.x);
    y.y = (Y0.y + Y1.y) + (Y2.y + Y3.y);

    // ---- Phase 3: replay exact recurrence from Y_s, write y ----
    #pragma unroll
    for (int k = 0; k < SEGLEN; ++k) {
        op[base + k * D2] = y;
        y.x = f * y.x + xa[k].x;
        y.y = f * y.y + xa[k].y;
    }
}

// ---------- Fallback (verified R4 path, 36 us) if ws_size is too small ----------
__device__ float g_carry[SEGS * D];

__global__ __launch_bounds__(256)
void comb_carry(const float* __restrict__ x, const float* __restrict__ fptr) {
    const float f = fptr[0];
    const int c4 = (blockIdx.x & 3) * 256 + threadIdx.x;
    const int s  = blockIdx.x >> 2;
    const float4* __restrict__ xp = (const float4*)x;
    const int base = s * SEGLEN * D4 + c4;
    float4 acc = make_float4(0.f, 0.f, 0.f, 0.f);
    #pragma unroll 8
    for (int k = 0; k < SEGLEN; ++k) {
        float4 a = xp[base + k * D4];
        acc.x = f * acc.x + a.x; acc.y = f * acc.y + a.y;
        acc.z = f * acc.z + a.z; acc.w = f * acc.w + a.w;
    }
    ((float4*)g_carry)[s * D4 + c4] = acc;
}

__global__ __launch_bounds__(256)
void comb_scan_emit(const float* __restrict__ x, const float* __restrict__ fptr,
                    float* __restrict__ out) {
    const float f = fptr[0];
    const int c4 = (blockIdx.x & 3) * 256 + threadIdx.x;
    const int s  = blockIdx.x >> 2;
    const float4* __restrict__ xp = (const float4*)x;
    float4* __restrict__ op = (float4*)out;
    const int base = s * SEGLEN * D4 + c4;
    float4 xa[SEGLEN];
    #pragma unroll
    for (int k = 0; k < SEGLEN; ++k) xa[k] = xp[base + k * D4];
    float fL = f * f; fL = fL * fL; fL = fL * fL; fL = fL * fL; fL = fL * fL;
    const float fL2 = fL * fL, fL4 = fL2 * fL2;
    const float4* __restrict__ cp = (const float4*)g_carry;
    float4 Y0 = make_float4(0.f, 0.f, 0.f, 0.f), Y1 = Y0, Y2 = Y0, Y3 = Y0;
    float w = 1.f;
    int t = s - 1;
    #pragma unroll 4
    for (; t >= 3; t -= 4) {
        float4 C0 = cp[(t    ) * D4 + c4];
        float4 C1 = cp[(t - 1) * D4 + c4];
        float4 C2 = cp[(t - 2) * D4 + c4];
        float4 C3 = cp[(t - 3) * D4 + c4];
        const float w0 = w, w1 = w * fL, w2 = w * fL2, w3 = w1 * fL2;
        Y0.x += w0 * C0.x; Y0.y += w0 * C0.y; Y0.z += w0 * C0.z; Y0.w += w0 * C0.w;
        Y1.x += w1 * C1.x; Y1.y += w1 * C1.y; Y1.z += w1 * C1.z; Y1.w += w1 * C1.w;
        Y2.x += w2 * C2.x; Y2.y += w2 * C2.y; Y2.z += w2 * C2.z; Y2.w += w2 * C2.w;
        Y3.x += w3 * C3.x; Y3.y += w3 * C3.y; Y3.z += w3 * C3.z; Y3.w += w3 * C3.w;
        w = w * fL4;
    }
    for (; t >= 0; --t) {
        float4 Ct = cp[t * D4 + c4];
        Y0.x += w * Ct.x; Y0.y += w * Ct.y; Y0.z += w * Ct.z; Y0.w += w * Ct.w;
        w *= fL;
    }
    float4 y;
    y.x = (Y0.x + Y1.x) + (Y2.x + Y3.x);
    y.y = (Y0.y + Y1.y) + (Y2.y + Y3.y);
    y.z = (Y0.z + Y1.z) + (Y2.z + Y3.z);
    y.w = (Y0.w + Y1.w) + (Y2.w + Y3.w);
    #pragma unroll
    for (int k = 0; k < SEGLEN; ++k) {
        op[base + k * D4] = y;
        y.x = f * y.x + xa[k].x; y.y = f * y.y + xa[k].y;
        y.z = f * y.z + xa[k].z; y.w = f * y.w + xa[k].w;
    }
}

extern "C" void kernel_launch(void* const* d_in, const int* in_sizes, int n_in,
                              void* d_out, int out_size, void* d_ws, size_t ws_size,
                              hipStream_t stream) {
    const float* x = (const float*)d_in[0];
    const float* f = (const float*)d_in[1];
    float* out = (float*)d_out;
    (void)in_sizes; (void)n_in; (void)out_size;

    if (ws_size >= (size_t)WS_NEEDED) {
        // zero ticket + flags (first 8 KB); carries are write-before-read
        hipMemsetAsync(d_ws, 0, WS_CARRY_OFF, stream);
        unsigned int* ws_u32 = (unsigned int*)d_ws;
        float2* carries = (float2*)((char*)d_ws + WS_CARRY_OFF);
        comb_fused<<<dim3(SEGS * GROUPS), dim3(256), 0, stream>>>(
            x, f, out, ws_u32, carries);
    } else {
        dim3 blk(256);
        comb_carry<<<dim3(SEGS * 4), blk, 0, stream>>>(x, f);
        comb_scan_emit<<<dim3(SEGS * 4), blk, 0, stream>>>(x, f, out);
    }
}

// Round 9
// 38.347 us; speedup vs baseline: 2.2079x; 2.2079x over previous
//
#include <hip/hip_runtime.h>

// Comb filter: y[n] = x[n-D] + f*y[n-D], y[n]=0 for n<D.
// N = 16777216, D = 4096 -> 4096 independent chains of K = 4096 steps each.
// Chain c, step k: a_k = x[k*D + c]; y_0 = 0; y_{k+1} = f*y_k + a_k;
// output[k*D + c] = y_k.
//
// Two plain kernels (kernel-boundary coherence; no atomics/flags/memset):
//   K1 carry: per (segment s, chain-pair c2) C_s = Horner over SEGLEN=64
//             steps. Reads x 64 MiB, writes 1 MiB carries.
//   K2 scan+emit: Y_s = sum_{t<s} fL^(s-1-t) C_t (order-free weighted sum,
//             descending t, 4 accumulators -- the R4-verified association),
//             then replay SEGLEN steps STREAMING x (L3-hot from K1; no
//             register preload), writing y.
// R4->R9 delta: SEGS 128->64 cuts aggregate lookback traffic 130MB->32MB;
// dropping the xa[] preload cuts K2 VGPR ~170->~40 (full occupancy) and
// lets the replay loop pipeline load/store streams.
// R6-R8 lesson (abandoned): flag-synchronized single-pass leaves the machine
// ~95% idle regardless of coherence idiom; two-pass + L3 residency wins.

#define N_TOTAL 16777216
#define D       4096
#define K_STEPS (N_TOTAL / D)    // 4096
#define SEGS    64               // segments per chain
#define SEGLEN  (K_STEPS / SEGS) // 64 steps per segment
#define D2      (D / 2)          // 2048 float2 per k-row

// 1 MiB scratch in a device global (fully rewritten every call).
__device__ float g_carry[SEGS * D];

__global__ __launch_bounds__(256)
void comb_carry(const float* __restrict__ x, const float* __restrict__ fptr) {
    const float f = fptr[0];
    const int c2 = (blockIdx.x & 7) * 256 + threadIdx.x;  // 0..2047
    const int s  = blockIdx.x >> 3;                       // 0..63
    const float2* __restrict__ xp = (const float2*)x;
    const int base = s * SEGLEN * D2 + c2;

    float2 acc = make_float2(0.f, 0.f);
    #pragma unroll 8
    for (int k = 0; k < SEGLEN; ++k) {
        float2 a = xp[base + k * D2];
        acc.x = f * acc.x + a.x;
        acc.y = f * acc.y + a.y;
    }
    ((float2*)g_carry)[s * D2 + c2] = acc;
}

__global__ __launch_bounds__(256)
void comb_scan_emit(const float* __restrict__ x, const float* __restrict__ fptr,
                    float* __restrict__ out) {
    const float f = fptr[0];
    const int c2 = (blockIdx.x & 7) * 256 + threadIdx.x;  // 0..2047
    const int s  = blockIdx.x >> 3;                       // 0..63
    const float2* __restrict__ xp = (const float2*)x;
    float2* __restrict__ op = (float2*)out;

    // fL = f^SEGLEN via 6 squarings (SEGLEN = 64)
    float fL = f * f;
    fL = fL * fL; fL = fL * fL; fL = fL * fL; fL = fL * fL; fL = fL * fL;
    const float fL2 = fL * fL;
    const float fL4 = fL2 * fL2;

    // Segment-start state: order-free weighted sum over earlier carries
    //   Y_s = sum_{t=0}^{s-1} fL^(s-1-t) * C_t
    // descending t, windows of 4, fixed association (verified R4-R8).
    const float2* __restrict__ cp = (const float2*)g_carry;
    float2 Y0 = make_float2(0.f, 0.f), Y1 = Y0, Y2 = Y0, Y3 = Y0;
    float w = 1.f;
    int t = s - 1;
    for (; t >= 3; t -= 4) {
        float2 C0 = cp[(t    ) * D2 + c2];
        float2 C1 = cp[(t - 1) * D2 + c2];
        float2 C2 = cp[(t - 2) * D2 + c2];
        float2 C3 = cp[(t - 3) * D2 + c2];
        const float w0 = w, w1 = w * fL, w2 = w * fL2, w3 = w1 * fL2;
        Y0.x += w0 * C0.x; Y0.y += w0 * C0.y;
        Y1.x += w1 * C1.x; Y1.y += w1 * C1.y;
        Y2.x += w2 * C2.x; Y2.y += w2 * C2.y;
        Y3.x += w3 * C3.x; Y3.y += w3 * C3.y;
        w = w * fL4;
    }
    for (; t >= 0; --t) {
        float2 Ct = cp[t * D2 + c2];
        Y0.x += w * Ct.x; Y0.y += w * Ct.y;
        w *= fL;
    }
    float2 y;
    y.x = (Y0.x + Y1.x) + (Y2.x + Y3.x);
    y.y = (Y0.y + Y1.y) + (Y2.y + Y3.y);

    // Replay exact recurrence, STREAMING x (L3-hot), write y.
    const int base = s * SEGLEN * D2 + c2;
    #pragma unroll 8
    for (int k = 0; k < SEGLEN; ++k) {
        const int idx = base + k * D2;
        op[idx] = y;
        float2 a = xp[idx];
        y.x = f * y.x + a.x;
        y.y = f * y.y + a.y;
    }
}

extern "C" void kernel_launch(void* const* d_in, const int* in_sizes, int n_in,
                              void* d_out, int out_size, void* d_ws, size_t ws_size,
                              hipStream_t stream) {
    const float* x = (const float*)d_in[0];
    const float* f = (const float*)d_in[1];
    float* out = (float*)d_out;
    (void)in_sizes; (void)n_in; (void)d_ws; (void)ws_size; (void)out_size;

    dim3 blk(256);
    dim3 grid(SEGS * 8);   // 512 blocks each
    comb_carry<<<grid, blk, 0, stream>>>(x, f);
    comb_scan_emit<<<grid, blk, 0, stream>>>(x, f, out);
}

// Round 11
// 37.123 us; speedup vs baseline: 2.2807x; 1.0330x over previous
//
#include <hip/hip_runtime.h>

// Comb filter: y[n] = x[n-D] + f*y[n-D], y[n]=0 for n<D.
// N = 16777216, D = 4096 -> 4096 independent chains of K = 4096 steps each.
// Chain c, step k: a_k = x[k*D + c]; y_0 = 0; y_{k+1} = f*y_k + a_k;
// output[k*D + c] = y_k.
//
// Two kernels (R4 structure = best measured 36.0 us), plus:
//   * LOAD-BALANCED s-mapping in K2: blocks b and b+256 (co-resident on the
//     same CU at 2 blocks/CU) get segments s and 127-s, so every CU's
//     lookback work sums to the constant 127 rows. The old monotone mapping
//     gave per-CU work 64..190 -> duration set by the s~127 stragglers.
//   * nontemporal out-stores (via native ext_vector_type; HIP float4 is a
//     class and the builtin rejects it -- R10 compile fix).
// Thread-level arithmetic is unchanged -> bit-identical output (absmax 0).

#define N_TOTAL 16777216
#define D       4096
#define K_STEPS (N_TOTAL / D)    // 4096
#define SEGS    128              // segments per chain
#define SEGLEN  (K_STEPS / SEGS) // 32 steps per segment
#define D4      (D / 4)          // 1024 float4 per k-row

typedef float nfloat4 __attribute__((ext_vector_type(4)));

// 2 MiB scratch in a device global (fully rewritten every call).
__device__ float g_carry[SEGS * D];

__global__ __launch_bounds__(256)
void comb_carry(const float* __restrict__ x, const float* __restrict__ fptr) {
    const float f = fptr[0];
    const int c4 = (blockIdx.x & 3) * 256 + threadIdx.x;  // 0..1023
    const int s  = blockIdx.x >> 2;                       // 0..127
    const float4* __restrict__ xp = (const float4*)x;
    const int base = s * SEGLEN * D4 + c4;

    float4 acc = make_float4(0.f, 0.f, 0.f, 0.f);
    #pragma unroll 8
    for (int k = 0; k < SEGLEN; ++k) {
        float4 a = xp[base + k * D4];
        acc.x = f * acc.x + a.x;
        acc.y = f * acc.y + a.y;
        acc.z = f * acc.z + a.z;
        acc.w = f * acc.w + a.w;
    }
    ((float4*)g_carry)[s * D4 + c4] = acc;
}

__global__ __launch_bounds__(256)
void comb_scan_emit(const float* __restrict__ x, const float* __restrict__ fptr,
                    float* __restrict__ out) {
    const float f = fptr[0];

    // Balanced mapping: blocks b and b+256 -> segments s and SEGS-1-s.
    const int b    = blockIdx.x;          // 0..511
    const int half = b >> 8;              // 0 or 1
    const int i    = b & 255;             // 0..255
    const int s    = half ? (SEGS - 1) - (i >> 2) : (i >> 2);
    const int g    = i & 3;
    const int c4   = g * 256 + threadIdx.x;   // 0..1023

    const float4* __restrict__ xp = (const float4*)x;
    nfloat4* __restrict__ op = (nfloat4*)out;
    const int base = s * SEGLEN * D4 + c4;

    // Preload this segment's x into registers (independent loads, issued
    // first so their latency hides under the lookback below).
    float4 xa[SEGLEN];
    #pragma unroll
    for (int k = 0; k < SEGLEN; ++k) xa[k] = xp[base + k * D4];

    // fL = f^SEGLEN via 5 squarings (SEGLEN = 32)
    float fL = f * f;
    fL = fL * fL; fL = fL * fL; fL = fL * fL; fL = fL * fL;
    const float fL2 = fL * fL;
    const float fL4 = fL2 * fL2;

    // Order-free weighted lookback (descending t, windows of 4, fixed
    // association -- verified bit-exact R4-R9).
    const float4* __restrict__ cp = (const float4*)g_carry;
    float4 Y0 = make_float4(0.f, 0.f, 0.f, 0.f), Y1 = Y0, Y2 = Y0, Y3 = Y0;
    float w = 1.f;
    int t = s - 1;
    #pragma unroll 4
    for (; t >= 3; t -= 4) {
        float4 C0 = cp[(t    ) * D4 + c4];
        float4 C1 = cp[(t - 1) * D4 + c4];
        float4 C2 = cp[(t - 2) * D4 + c4];
        float4 C3 = cp[(t - 3) * D4 + c4];
        const float w0 = w, w1 = w * fL, w2 = w * fL2, w3 = w1 * fL2;
        Y0.x += w0 * C0.x; Y0.y += w0 * C0.y; Y0.z += w0 * C0.z; Y0.w += w0 * C0.w;
        Y1.x += w1 * C1.x; Y1.y += w1 * C1.y; Y1.z += w1 * C1.z; Y1.w += w1 * C1.w;
        Y2.x += w2 * C2.x; Y2.y += w2 * C2.y; Y2.z += w2 * C2.z; Y2.w += w2 * C2.w;
        Y3.x += w3 * C3.x; Y3.y += w3 * C3.y; Y3.z += w3 * C3.z; Y3.w += w3 * C3.w;
        w = w * fL4;
    }
    for (; t >= 0; --t) {
        float4 Ct = cp[t * D4 + c4];
        Y0.x += w * Ct.x; Y0.y += w * Ct.y; Y0.z += w * Ct.z; Y0.w += w * Ct.w;
        w *= fL;
    }
    float4 y;
    y.x = (Y0.x + Y1.x) + (Y2.x + Y3.x);
    y.y = (Y0.y + Y1.y) + (Y2.y + Y3.y);
    y.z = (Y0.z + Y1.z) + (Y2.z + Y3.z);
    y.w = (Y0.w + Y1.w) + (Y2.w + Y3.w);

    // Replay exact recurrence from Y_s; nontemporal stores keep x L3-hot.
    #pragma unroll
    for (int k = 0; k < SEGLEN; ++k) {
        nfloat4 yv;
        yv.x = y.x; yv.y = y.y; yv.z = y.z; yv.w = y.w;
        __builtin_nontemporal_store(yv, &op[base + k * D4]);
        y.x = f * y.x + xa[k].x;
        y.y = f * y.y + xa[k].y;
        y.z = f * y.z + xa[k].z;
        y.w = f * y.w + xa[k].w;
    }
}

extern "C" void kernel_launch(void* const* d_in, const int* in_sizes, int n_in,
                              void* d_out, int out_size, void* d_ws, size_t ws_size,
                              hipStream_t stream) {
    const float* x = (const float*)d_in[0];
    const float* f = (const float*)d_in[1];
    float* out = (float*)d_out;
    (void)in_sizes; (void)n_in; (void)d_ws; (void)ws_size; (void)out_size;

    dim3 blk(256);
    dim3 grid(SEGS * 4);   // 512 blocks each
    comb_carry<<<grid, blk, 0, stream>>>(x, f);
    comb_scan_emit<<<grid, blk, 0, stream>>>(x, f, out);
}